// Round 1
// baseline (1821.392 us; speedup 1.0000x reference)
//
#include <hip/hip_runtime.h>

#define V 80000
#define E 640000
#define D 128
#define NREL 500
#define HALF (E/2)
#define NB_NODES 512
#define NBE 1024

__device__ __forceinline__ unsigned ord_enc(float f) {
  unsigned u = __float_as_uint(f);
  return (u & 0x80000000u) ? ~u : (u | 0x80000000u);
}
__device__ __forceinline__ float ord_dec(unsigned m) {
  return (m & 0x80000000u) ? __uint_as_float(m ^ 0x80000000u) : __uint_as_float(~m);
}

// init emax (ordered -inf), esum, bn accumulators
__global__ void k_init(unsigned* emaxu, float* esum, float* colsum, float* colsumsq) {
  int i = blockIdx.x * 256 + threadIdx.x;
  if (i < V) { emaxu[i] = 0x007FFFFFu; esum[i] = 0.f; }
  if (i < D) { colsum[i] = 0.f; colsumsq[i] = 0.f; }
}

// out1 = rel @ w_rel ; rw[r] = rel[r] . attn_w[128:256]
__global__ void k_rel(const float* __restrict__ rel, const float* __restrict__ w_rel,
                      const float* __restrict__ attn_w, float* __restrict__ out1,
                      float* __restrict__ rw) {
  __shared__ float rs[D];
  __shared__ float red[D];
  int r = blockIdx.x, n = threadIdx.x;
  rs[n] = rel[r * D + n];
  __syncthreads();
  float acc = 0.f;
  #pragma unroll 8
  for (int j = 0; j < D; ++j) acc += rs[j] * w_rel[j * D + n];
  out1[r * D + n] = acc;
  red[n] = rs[n] * attn_w[D + n];
  __syncthreads();
  if (n == 0) {
    float s = 0.f;
    for (int j = 0; j < D; ++j) s += red[j];
    rw[r] = s;
  }
}

// Mloop[j,n] = sum_k loop_rel[(j+k)%128] * loop_w[k,n]
__global__ void k_mloop(const float* __restrict__ loop_rel, const float* __restrict__ loop_w,
                        float* __restrict__ mloop) {
  __shared__ float ls[D];
  int j = blockIdx.x, n = threadIdx.x;
  ls[n] = loop_rel[n];
  __syncthreads();
  float acc = 0.f;
  #pragma unroll 8
  for (int k = 0; k < D; ++k) acc += ls[(j + k) & 127] * loop_w[k * D + n];
  mloop[j * D + n] = acc;
}

// per node: sxw, dxw projections; out0 init = (x @ Mloop)/3 + bias
__global__ __launch_bounds__(256) void k_nodes(const float* __restrict__ x,
    const float* __restrict__ mloop, const float* __restrict__ attn_w,
    const float* __restrict__ bias, float* __restrict__ out0,
    float* __restrict__ sxw, float* __restrict__ dxw) {
  __shared__ float sW[D * D];
  __shared__ float xrow[4][D];
  int tid = threadIdx.x;
  for (int idx = tid; idx < D * D; idx += 256) sW[idx] = mloop[idx];
  __syncthreads();
  int wid = tid >> 6, lane = tid & 63;
  float ws0 = attn_w[lane], ws1 = attn_w[64 + lane];
  float wd0 = attn_w[256 + lane], wd1 = attn_w[320 + lane];
  float b0 = bias[2 * lane], b1 = bias[2 * lane + 1];
  float* xr = xrow[wid];
  for (int v = blockIdx.x * 4 + wid; v < V; v += NB_NODES * 4) {
    float x0 = x[v * D + lane], x1 = x[v * D + 64 + lane];
    float ps = x0 * ws0 + x1 * ws1;
    float pd = x0 * wd0 + x1 * wd1;
    #pragma unroll
    for (int off = 32; off; off >>= 1) { ps += __shfl_xor(ps, off); pd += __shfl_xor(pd, off); }
    if (lane == 0) { sxw[v] = ps; dxw[v] = pd; }
    xr[lane] = x0; xr[64 + lane] = x1;
    asm volatile("s_waitcnt lgkmcnt(0)" ::: "memory");
    float a0 = 0.f, a1 = 0.f;
    for (int j4 = 0; j4 < 32; ++j4) {
      float4 xv = *(const float4*)&xr[j4 * 4];
      #pragma unroll
      for (int jj = 0; jj < 4; ++jj) {
        int j = j4 * 4 + jj;
        float xs = (jj == 0) ? xv.x : (jj == 1) ? xv.y : (jj == 2) ? xv.z : xv.w;
        float2 wv = *(const float2*)&sW[j * D + 2 * lane];
        a0 += xs * wv.x; a1 += xs * wv.y;
      }
    }
    out0[v * D + 2 * lane]     = a0 * (1.f / 3.f) + b0;
    out0[v * D + 2 * lane + 1] = a1 * (1.f / 3.f) + b1;
    asm volatile("s_waitcnt lgkmcnt(0)" ::: "memory");
  }
}

// attention logits + segment max
__global__ void k_edge_e(const int* __restrict__ src, const int* __restrict__ dst,
                         const int* __restrict__ et, const float* __restrict__ sxw,
                         const float* __restrict__ dxw, const float* __restrict__ rw,
                         float* __restrict__ evals, unsigned* __restrict__ emaxu) {
  int i = blockIdx.x * 256 + threadIdx.x;
  if (i >= E) return;
  float ev = sxw[src[i]] + rw[et[i]] + dxw[dst[i]];
  ev = ev >= 0.f ? ev : 0.01f * ev;
  evals[i] = ev;
  atomicMax(&emaxu[dst[i]], ord_enc(ev));
}

// ee = exp(e - emax[dst]); esum += ee   (evals overwritten in place with ee)
__global__ void k_edge_ee(const int* __restrict__ dst, float* __restrict__ evals,
                          const unsigned* __restrict__ emaxu, float* __restrict__ esum) {
  int i = blockIdx.x * 256 + threadIdx.x;
  if (i >= E) return;
  int d = dst[i];
  float m = ord_dec(emaxu[d]);
  float xv = __expf(evals[i] - m);
  evals[i] = xv;
  atomicAdd(&esum[d], xv);
}

// main: per-edge ccorr -> matmul (LDS W) -> softmax -> scaled atomic scatter
__global__ __launch_bounds__(256) void k_msg(const float* __restrict__ x,
    const float* __restrict__ rel, const float* __restrict__ in_w,
    const float* __restrict__ out_w, const float* __restrict__ edge_norm,
    const int* __restrict__ src, const int* __restrict__ dst, const int* __restrict__ et,
    const float* __restrict__ evals, const float* __restrict__ esum,
    float* __restrict__ out0) {
  __shared__ float sW[D * D];
  __shared__ float As[4][D];
  __shared__ float Bs[4][2 * D];
  __shared__ float Es[4][D];
  int tid = threadIdx.x;
  int halfIdx = (blockIdx.x >= NBE / 2) ? 1 : 0;
  const float* Wm = halfIdx ? out_w : in_w;
  for (int idx = tid; idx < D * D; idx += 256) sW[idx] = Wm[idx];
  __syncthreads();
  int wid = tid >> 6, lane = tid & 63;
  int ebase = halfIdx ? HALF : 0;
  float* A = As[wid];
  float* B = Bs[wid];
  float* Ee = Es[wid];
  for (int k = (blockIdx.x & (NBE / 2 - 1)) * 4 + wid; k < HALF; k += (NBE / 2) * 4) {
    int i = ebase + k;
    int s = src[i], d = dst[i], t = et[i];
    float en = edge_norm[i];
    float alpha = evals[i] / esum[d];
    float a0 = x[s * D + lane], a1 = x[s * D + 64 + lane];
    float r0 = rel[t * D + lane], r1 = rel[t * D + 64 + lane];
    A[lane] = a0; A[64 + lane] = a1;
    B[lane] = r0; B[64 + lane] = r1; B[128 + lane] = r0; B[192 + lane] = r1;
    asm volatile("s_waitcnt lgkmcnt(0)" ::: "memory");
    // ccorr: c[k] = sum_j a[j] * b[(j+k)%128], this lane: k=lane, k=lane+64
    float c0 = 0.f, c1 = 0.f;
    for (int j4 = 0; j4 < 32; ++j4) {
      float4 av = *(const float4*)&A[j4 * 4];
      #pragma unroll
      for (int jj = 0; jj < 4; ++jj) {
        int j = j4 * 4 + jj;
        float as = (jj == 0) ? av.x : (jj == 1) ? av.y : (jj == 2) ? av.z : av.w;
        c0 += as * B[j + lane];
        c1 += as * B[j + 64 + lane];
      }
    }
    Ee[lane] = c0; Ee[64 + lane] = c1;
    asm volatile("s_waitcnt lgkmcnt(0)" ::: "memory");
    // msg = edh @ W, this lane: cols 2*lane, 2*lane+1
    float m0 = 0.f, m1 = 0.f;
    for (int j4 = 0; j4 < 32; ++j4) {
      float4 ev4 = *(const float4*)&Ee[j4 * 4];
      #pragma unroll
      for (int jj = 0; jj < 4; ++jj) {
        int j = j4 * 4 + jj;
        float es = (jj == 0) ? ev4.x : (jj == 1) ? ev4.y : (jj == 2) ? ev4.z : ev4.w;
        float2 wv = *(const float2*)&sW[j * D + 2 * lane];
        m0 += es * wv.x; m1 += es * wv.y;
      }
    }
    // row softmax over 128 cols
    float mx = fmaxf(m0, m1);
    #pragma unroll
    for (int off = 32; off; off >>= 1) mx = fmaxf(mx, __shfl_xor(mx, off));
    float e0 = __expf(m0 - mx), e1 = __expf(m1 - mx);
    float ss = e0 + e1;
    #pragma unroll
    for (int off = 32; off; off >>= 1) ss += __shfl_xor(ss, off);
    float sc = en * alpha / (3.f * ss);
    atomicAdd(&out0[d * D + 2 * lane], e0 * sc);
    atomicAdd(&out0[d * D + 2 * lane + 1], e1 * sc);
    asm volatile("s_waitcnt lgkmcnt(0)" ::: "memory");
  }
}

__global__ void k_bn_stats(const float* __restrict__ out0, float* __restrict__ colsum,
                           float* __restrict__ colsumsq) {
  int tid = threadIdx.x;
  int col = tid & 127;
  int v0 = blockIdx.x * 2 + (tid >> 7);
  float s = 0.f, s2 = 0.f;
  for (int v = v0; v < V; v += 1024) {
    float val = out0[v * D + col];
    s += val; s2 += val * val;
  }
  atomicAdd(&colsum[col], s);
  atomicAdd(&colsumsq[col], s2);
}

__global__ void k_bn_norm(float* __restrict__ out0, const float* __restrict__ colsum,
                          const float* __restrict__ colsumsq) {
  int i = blockIdx.x * 256 + threadIdx.x;
  if (i >= V * D) return;
  int c = i & 127;
  float mean = colsum[c] * (1.f / V);
  float var = colsumsq[c] * (1.f / V) - mean * mean;
  out0[i] = (out0[i] - mean) * rsqrtf(var + 1e-5f);
}

extern "C" void kernel_launch(void* const* d_in, const int* in_sizes, int n_in,
                              void* d_out, int out_size, void* d_ws, size_t ws_size,
                              hipStream_t stream) {
  const float* x        = (const float*)d_in[0];
  const float* rel      = (const float*)d_in[4];
  const float* enorm    = (const float*)d_in[5];
  const float* in_w     = (const float*)d_in[6];
  const float* out_w    = (const float*)d_in[7];
  const float* loop_w   = (const float*)d_in[8];
  const float* w_rel    = (const float*)d_in[9];
  const float* loop_rel = (const float*)d_in[10];
  const float* attn_w   = (const float*)d_in[11];
  const float* bias     = (const float*)d_in[12];
  const int* src = (const int*)d_in[13];
  const int* dst = (const int*)d_in[14];
  const int* et  = (const int*)d_in[15];

  float* out0 = (float*)d_out;           // [V,128]
  float* out1 = out0 + (size_t)V * D;    // [500,128]

  float* base = (float*)d_ws;
  float* sxw = base;
  float* dxw = base + V;
  float* esum = base + 2 * V;
  unsigned* emaxu = (unsigned*)(base + 3 * V);
  float* evals = base + 4 * V;           // [E], later holds ee
  float* rw = base + 4 * V + E;          // [500]
  float* mloop = rw + 512;               // [128*128]
  float* colsum = mloop + D * D;         // [128]
  float* colsumsq = colsum + D;          // [128]

  k_init<<<(V + 255) / 256, 256, 0, stream>>>(emaxu, esum, colsum, colsumsq);
  k_rel<<<NREL, D, 0, stream>>>(rel, w_rel, attn_w, out1, rw);
  k_mloop<<<D, D, 0, stream>>>(loop_rel, loop_w, mloop);
  k_nodes<<<NB_NODES, 256, 0, stream>>>(x, mloop, attn_w, bias, out0, sxw, dxw);
  k_edge_e<<<(E + 255) / 256, 256, 0, stream>>>(src, dst, et, sxw, dxw, rw, evals, emaxu);
  k_edge_ee<<<(E + 255) / 256, 256, 0, stream>>>(dst, evals, emaxu, esum);
  k_msg<<<NBE, 256, 0, stream>>>(x, rel, in_w, out_w, enorm, src, dst, et, evals, esum, out0);
  k_bn_stats<<<512, 256, 0, stream>>>(out0, colsum, colsumsq);
  k_bn_norm<<<(V * D + 255) / 256, 256, 0, stream>>>(out0, colsum, colsumsq);
}